// Round 2
// baseline (2228.345 us; speedup 1.0000x reference)
//
#include <hip/hip_runtime.h>
#include <cstddef>
#include <cstdint>

// Problem constants
constexpr int MAX_  = 2048;
constexpr int OUT_  = 256;
constexpr int NS_   = 16;
constexpr int D_    = 1024;
constexpr int H_    = 16;
constexpr int HD_   = 64;
constexpr int FFN_  = 4096;
constexpr int TOTAL_= 2064;   // MAX + NS
constexpr int QL_   = 272;    // OUT + NS
constexpr int B_    = 4;

// Workspace layout (floats)
constexpr size_t OFF_XN  = 0;                       // 4*2064*1024 = 8454144  (reused later)
constexpr size_t OFF_TS  = 0;                       // 1024*4096  = 4194304  (overlay on XN)
constexpr size_t OFF_TNS = 4194304;                 // 4*16*4096  = 262144   (overlay)
constexpr size_t OFF_PF1 = 4456448;                 // 16*8*4*4096 = 2097152 (overlay)
constexpr size_t OFF_PF2 = 6553600;                 // 16*16*4*1024 = 1048576(overlay)
constexpr size_t OFF_Q   = 8454144;                 // 4*272*1024 = 1114112
constexpr size_t OFF_K   = 9568256;                 // 4*2064*1024
constexpr size_t OFF_V   = 18022400;                // 4*2064*1024
constexpr size_t OFF_H1  = 26476544;                // 4*272*1024
constexpr size_t OFF_HN  = 27590656;                // 4*272*1024
constexpr size_t OFF_PQKV= 28704768;                // 3*16*8*4*1024 = 1572864
// total = 30277632 floats = 121.1 MB

#define DEV __device__ __forceinline__

DEV float wave_sum(float v) {
#pragma unroll
  for (int off = 32; off > 0; off >>= 1) v += __shfl_xor(v, off);
  return v;
}
DEV float wave_max(float v) {
#pragma unroll
  for (int off = 32; off > 0; off >>= 1) v = fmaxf(v, __shfl_xor(v, off));
  return v;
}

// ---------------- RMSNorm over all TOTAL rows ----------------
__global__ __launch_bounds__(256) void k_rmsnorm(const float* __restrict__ x,
                                                 const float* __restrict__ w,
                                                 float* __restrict__ y) {
  int row = blockIdx.x;
  const float4 v = reinterpret_cast<const float4*>(x + (size_t)row * D_)[threadIdx.x];
  float ss = v.x * v.x + v.y * v.y + v.z * v.z + v.w * v.w;
  ss = wave_sum(ss);
  __shared__ float red[4];
  int lane = threadIdx.x & 63, wv = threadIdx.x >> 6;
  if (lane == 0) red[wv] = ss;
  __syncthreads();
  float tot = red[0] + red[1] + red[2] + red[3];
  float sc = 1.0f / sqrtf(tot * (1.0f / D_) + 1e-6f);
  const float4 w4 = reinterpret_cast<const float4*>(w)[threadIdx.x];
  float4 o;
  o.x = v.x * sc * w4.x; o.y = v.y * sc * w4.y;
  o.z = v.z * sc * w4.z; o.w = v.w * sc * w4.w;
  reinterpret_cast<float4*>(y + (size_t)row * D_)[threadIdx.x] = o;
}

// ---------------- residual add + RMSNorm ----------------
__global__ __launch_bounds__(256) void k_resid_rms(const float* __restrict__ x,
                                                   const float* __restrict__ w,
                                                   float* __restrict__ h1,
                                                   float* __restrict__ hn) {
  int row = blockIdx.x;              // b*272 + r
  int b = row / QL_, r = row - b * QL_;
  size_t xoff = ((size_t)(b * TOTAL_ + (MAX_ - OUT_) + r)) * D_;
  float4 a = reinterpret_cast<float4*>(h1 + (size_t)row * D_)[threadIdx.x];
  const float4 xv = reinterpret_cast<const float4*>(x + xoff)[threadIdx.x];
  a.x += xv.x; a.y += xv.y; a.z += xv.z; a.w += xv.w;
  reinterpret_cast<float4*>(h1 + (size_t)row * D_)[threadIdx.x] = a;
  float ss = a.x * a.x + a.y * a.y + a.z * a.z + a.w * a.w;
  ss = wave_sum(ss);
  __shared__ float red[4];
  int lane = threadIdx.x & 63, wv = threadIdx.x >> 6;
  if (lane == 0) red[wv] = ss;
  __syncthreads();
  float tot = red[0] + red[1] + red[2] + red[3];
  float sc = 1.0f / sqrtf(tot * (1.0f / D_) + 1e-6f);
  const float4 w4 = reinterpret_cast<const float4*>(w)[threadIdx.x];
  float4 o;
  o.x = a.x * sc * w4.x; o.y = a.y * sc * w4.y;
  o.z = a.z * sc * w4.z; o.w = a.w * sc * w4.w;
  reinterpret_cast<float4*>(hn + (size_t)row * D_)[threadIdx.x] = o;
}

// ---------------- tiled SGEMM (BK=16, float4 staging), templated epilogue ----
// MODE 0: QKV  (A = xn with row map b*2064+t; scatter to q/k/v with bias)
// MODE 1: FFN1 (A = hn with row map b*272+r; C = relu(acc+bias))
// MODE 2: FFN2 (A = t_s contiguous; C = d_out rows with bias + h1 residual)
template <int BM, int BN, int TM, int TN, int MODE>
__global__ __launch_bounds__(256) void sgemm(const float* __restrict__ A,
                                             const float* __restrict__ Bm,
                                             const float* __restrict__ bias,
                                             float* __restrict__ C0,
                                             float* __restrict__ C1,
                                             float* __restrict__ C2,
                                             const float* __restrict__ extra,
                                             int M, int N, int K) {
  constexpr int BK = 16;
  __shared__ float As[BK][BM + 4];
  __shared__ float Bs[BK][BN + 4];
  const int tid = threadIdx.x;
  constexpr int NTX = BN / TN;             // threads along n
  const int tx = tid % NTX;
  const int ty = tid / NTX;
  const int m0 = blockIdx.y * BM;
  const int n0 = blockIdx.x * BN;

  if (MODE == 0) {
    // Q columns only needed for tokens >= 1792
    int t0 = m0 & (MAX_ - 1);
    if ((n0 + BN <= D_) && (t0 + BM <= MAX_ - OUT_)) return;
  }

  float acc[TM][TN];
#pragma unroll
  for (int i = 0; i < TM; ++i)
#pragma unroll
    for (int j = 0; j < TN; ++j) acc[i][j] = 0.f;

  for (int k0 = 0; k0 < K; k0 += BK) {
    // A tile: BM rows x 16 floats = BM*4 float4s; store transposed to LDS.
    // Scalar LDS stores are 2-way bank-aliased (free on CDNA4).
#pragma unroll
    for (int idx = tid; idx < BM * 4; idx += 256) {
      int r = idx >> 2;
      int c = idx & 3;
      int m = m0 + r;
      int arow;
      if (MODE == 0)      arow = ((m >> 11) * TOTAL_) + (m & (MAX_ - 1));
      else if (MODE == 1) arow = ((m >> 8) * QL_) + (m & 255);
      else                arow = m;
      const float4 v = *reinterpret_cast<const float4*>(A + (size_t)arow * K + k0 + 4 * c);
      As[4 * c + 0][r] = v.x;
      As[4 * c + 1][r] = v.y;
      As[4 * c + 2][r] = v.z;
      As[4 * c + 3][r] = v.w;
    }
    // B tile: 16 x BN floats = 4*BN float4s; contiguous along n.
#pragma unroll
    for (int idx = tid; idx < 4 * BN; idx += 256) {
      int kk = idx / (BN / 4);
      int nq = idx % (BN / 4);
      const float4 v = *reinterpret_cast<const float4*>(Bm + (size_t)(k0 + kk) * N + n0 + 4 * nq);
      *reinterpret_cast<float4*>(&Bs[kk][4 * nq]) = v;
    }
    __syncthreads();
#pragma unroll
    for (int kk = 0; kk < BK; ++kk) {
      float a[TM], b[TN];
#pragma unroll
      for (int i = 0; i < TM; ++i) a[i] = As[kk][ty * TM + i];
#pragma unroll
      for (int j = 0; j < TN; ++j) b[j] = Bs[kk][tx * TN + j];
#pragma unroll
      for (int i = 0; i < TM; ++i)
#pragma unroll
        for (int j = 0; j < TN; ++j) acc[i][j] = fmaf(a[i], b[j], acc[i][j]);
    }
    __syncthreads();
  }

#pragma unroll
  for (int i = 0; i < TM; ++i) {
    int m = m0 + ty * TM + i;
#pragma unroll
    for (int j = 0; j < TN; ++j) {
      int n = n0 + tx * TN + j;
      float v = acc[i][j] + bias[n];
      if (MODE == 0) {
        int b = m >> 11, t = m & (MAX_ - 1);
        if (n < D_) {
          if (t >= MAX_ - OUT_)
            C0[((size_t)(b * QL_ + (t - (MAX_ - OUT_)))) * D_ + n] = v;
        } else if (n < 2 * D_) {
          C1[((size_t)(b * TOTAL_ + t)) * D_ + (n - D_)] = v;
        } else {
          C2[((size_t)(b * TOTAL_ + t)) * D_ + (n - 2 * D_)] = v;
        }
      } else if (MODE == 1) {
        C0[(size_t)m * N + n] = fmaxf(v, 0.f);
      } else {
        int b = m >> 8, r = m & 255;
        size_t oi = ((size_t)(b * QL_ + r)) * D_ + n;
        C0[oi] = v + extra[oi];
      }
    }
  }
}

// ---------------- ns q/k/v projections: split-K partials ----------------
// grid (chunk=8, n=16, proj=3); 256 thr; each block: 128 i's x 1024 o's x 4 b
__global__ __launch_bounds__(256) void k_nsproj_partial(const float* __restrict__ xn,
                                                        const float* __restrict__ wq,
                                                        const float* __restrict__ wk,
                                                        const float* __restrict__ wv,
                                                        float* __restrict__ part) {
  int chunk = blockIdx.x, n = blockIdx.y, proj = blockIdx.z;
  const float* W = (proj == 0) ? wq : ((proj == 1) ? wk : wv);
  __shared__ float xs[4][128];
  int i0 = chunk * 128;
  for (int idx = threadIdx.x; idx < 512; idx += 256) {
    int b = idx >> 7, ii = idx & 127;
    xs[b][ii] = xn[((size_t)(b * TOTAL_ + MAX_ + n)) * D_ + i0 + ii];
  }
  __syncthreads();
  float4 acc[4];
#pragma unroll
  for (int b = 0; b < 4; ++b) acc[b] = make_float4(0.f, 0.f, 0.f, 0.f);
  const float4* Wp = reinterpret_cast<const float4*>(W + (size_t)n * D_ * D_ + (size_t)i0 * D_) + threadIdx.x;
#pragma unroll 4
  for (int ii = 0; ii < 128; ++ii) {
    float4 w4 = Wp[(size_t)ii * (D_ / 4)];
#pragma unroll
    for (int b = 0; b < 4; ++b) {
      float xv = xs[b][ii];
      acc[b].x = fmaf(xv, w4.x, acc[b].x);
      acc[b].y = fmaf(xv, w4.y, acc[b].y);
      acc[b].z = fmaf(xv, w4.z, acc[b].z);
      acc[b].w = fmaf(xv, w4.w, acc[b].w);
    }
  }
  size_t base = (((size_t)(proj * 16 + n) * 8 + chunk) * 4) * D_;
#pragma unroll
  for (int b = 0; b < 4; ++b)
    reinterpret_cast<float4*>(part + base + (size_t)b * D_)[threadIdx.x] = acc[b];
}

__global__ __launch_bounds__(256) void k_nsproj_reduce(const float* __restrict__ part,
                                                       const float* __restrict__ bq,
                                                       const float* __restrict__ bk,
                                                       const float* __restrict__ bv,
                                                       float* __restrict__ q,
                                                       float* __restrict__ k,
                                                       float* __restrict__ v) {
  int gid = blockIdx.x * 256 + threadIdx.x;   // 3*16*4*256 = 49152
  int o4 = gid & 255;
  int b = (gid >> 8) & 3;
  int n = (gid >> 10) & 15;
  int proj = gid >> 14;
  float4 s = make_float4(0.f, 0.f, 0.f, 0.f);
  for (int c = 0; c < 8; ++c) {
    size_t pidx = (((size_t)(proj * 16 + n) * 8 + c) * 4 + b) * D_ + (size_t)o4 * 4;
    float4 p = *reinterpret_cast<const float4*>(part + pidx);
    s.x += p.x; s.y += p.y; s.z += p.z; s.w += p.w;
  }
  const float* bias = (proj == 0) ? bq : ((proj == 1) ? bk : bv);
  float4 bb = *reinterpret_cast<const float4*>(bias + (size_t)n * D_ + (size_t)o4 * 4);
  s.x += bb.x; s.y += bb.y; s.z += bb.z; s.w += bb.w;
  float* dst; size_t row;
  if (proj == 0)      { dst = q; row = (size_t)b * QL_ + OUT_ + n; }
  else if (proj == 1) { dst = k; row = (size_t)b * TOTAL_ + MAX_ + n; }
  else                { dst = v; row = (size_t)b * TOTAL_ + MAX_ + n; }
  *reinterpret_cast<float4*>(dst + row * D_ + (size_t)o4 * 4) = s;
}

// ---------------- RoPE in-place ----------------
__global__ __launch_bounds__(256) void k_rope(float* __restrict__ buf, int rowsPerB, int posOff) {
  int row = blockIdx.x;
  int r = row % rowsPerB;
  float pos = (float)(posOff + r);
  float* p = buf + (size_t)row * D_;
  for (int idx = threadIdx.x; idx < 512; idx += 256) {
    int h = idx >> 5;
    int j = idx & 31;
    float inv = __powf(10000.0f, -(float)(2 * j) / (float)HD_);
    float f = pos * inv;
    float c = cosf(f), s = sinf(f);
    float x1 = p[h * HD_ + j];
    float x2 = p[h * HD_ + 32 + j];
    p[h * HD_ + j]      = x1 * c - x2 * s;
    p[h * HD_ + 32 + j] = x2 * c + x1 * s;
  }
}

// ---------------- attention (flash-style, fp32) ----------------
// grid (qchunk=17, h=16, b=4); 256 thr = 4 waves; each wave: 4 q rows
__global__ __launch_bounds__(256) void k_attn(const float* __restrict__ q,
                                              const float* __restrict__ k,
                                              const float* __restrict__ v,
                                              const int* __restrict__ seqlen,
                                              float* __restrict__ o) {
  int qc = blockIdx.x, h = blockIdx.y, b = blockIdx.z;
  __shared__ float Qs[16][65];
  __shared__ float Ks[64][65];
  __shared__ float Vs[64][65];
  __shared__ float Ps[4][4][64];
  int tid = threadIdx.x, lane = tid & 63, w = tid >> 6;
  int q0 = qc * 16;

  for (int idx = tid; idx < 16 * 64; idx += 256) {
    int r = idx >> 6, d = idx & 63;
    Qs[r][d] = q[((size_t)(b * QL_ + q0 + r)) * D_ + h * HD_ + d] * 0.125f;
  }
  int L = seqlen[b];
  int kmin = MAX_ - L;
  int kmaxBlk = (MAX_ - OUT_) + q0 + 15;   // inclusive causal max for this block
  int c0 = kmin >> 6;
  int c1 = kmaxBlk >> 6;

  float m[4], l[4], oacc[4];
#pragma unroll
  for (int rr = 0; rr < 4; ++rr) { m[rr] = -1e30f; l[rr] = 0.f; oacc[rr] = 0.f; }

  for (int c = c0; c <= c1; ++c) {
    __syncthreads();
    for (int idx = tid; idx < 64 * 64; idx += 256) {
      int r = idx >> 6, d = idx & 63;
      int key = c * 64 + r;
      bool inb = key < TOTAL_;
      size_t koff = ((size_t)(b * TOTAL_ + (inb ? key : 0))) * D_ + h * HD_ + d;
      Ks[r][d] = inb ? k[koff] : 0.f;
      Vs[r][d] = inb ? v[koff] : 0.f;
    }
    __syncthreads();

    int key = c * 64 + lane;
    float sr[4];
#pragma unroll
    for (int rr = 0; rr < 4; ++rr) sr[rr] = 0.f;
#pragma unroll 8
    for (int d = 0; d < 64; ++d) {
      float kd = Ks[lane][d];
#pragma unroll
      for (int rr = 0; rr < 4; ++rr) sr[rr] = fmaf(Qs[(w << 2) + rr][d], kd, sr[rr]);
    }
#pragma unroll
    for (int rr = 0; rr < 4; ++rr) {
      int rAbs = q0 + (w << 2) + rr;
      bool valid = (key >= kmin) && (key <= (MAX_ - OUT_) + rAbs);
      float s = valid ? sr[rr] : -1e30f;
      float cm = wave_max(s);
      float mn = fmaxf(m[rr], cm);
      float p = valid ? __expf(s - mn) : 0.f;
      float fr = __expf(m[rr] - mn);
      float ps = wave_sum(p);
      l[rr] = l[rr] * fr + ps;
      m[rr] = mn;
      oacc[rr] *= fr;
      Ps[w][rr][lane] = p;
    }
#pragma unroll 4
    for (int kk = 0; kk < 64; ++kk) {
      float vv = Vs[kk][lane];
#pragma unroll
      for (int rr = 0; rr < 4; ++rr) oacc[rr] = fmaf(Ps[w][rr][kk], vv, oacc[rr]);
    }
  }
#pragma unroll
  for (int rr = 0; rr < 4; ++rr) {
    int rAbs = q0 + (w << 2) + rr;
    o[((size_t)(b * QL_ + rAbs)) * D_ + h * HD_ + lane] = oacc[rr] / l[rr];
  }
}

// ---------------- ns FFN: split-K partials ----------------
// w1: grid (chunk=8, otile=4, n=16)
__global__ __launch_bounds__(256) void k_ffn_ns_p1(const float* __restrict__ hn,
                                                   const float* __restrict__ w1,
                                                   float* __restrict__ part) {
  int chunk = blockIdx.x, ot = blockIdx.y, n = blockIdx.z;
  __shared__ float xs[4][128];
  int i0 = chunk * 128;
  for (int idx = threadIdx.x; idx < 512; idx += 256) {
    int b = idx >> 7, ii = idx & 127;
    xs[b][ii] = hn[((size_t)(b * QL_ + OUT_ + n)) * D_ + i0 + ii];
  }
  __syncthreads();
  float4 acc[4];
#pragma unroll
  for (int b = 0; b < 4; ++b) acc[b] = make_float4(0.f, 0.f, 0.f, 0.f);
  const float4* Wp = reinterpret_cast<const float4*>(w1 + (size_t)n * D_ * FFN_ + (size_t)i0 * FFN_ + (size_t)ot * 1024) + threadIdx.x;
#pragma unroll 4
  for (int ii = 0; ii < 128; ++ii) {
    float4 w4 = Wp[(size_t)ii * (FFN_ / 4)];
#pragma unroll
    for (int b = 0; b < 4; ++b) {
      float xv = xs[b][ii];
      acc[b].x = fmaf(xv, w4.x, acc[b].x);
      acc[b].y = fmaf(xv, w4.y, acc[b].y);
      acc[b].z = fmaf(xv, w4.z, acc[b].z);
      acc[b].w = fmaf(xv, w4.w, acc[b].w);
    }
  }
  size_t base = (((size_t)n * 8 + chunk) * 4) * FFN_ + (size_t)ot * 1024;
#pragma unroll
  for (int b = 0; b < 4; ++b)
    reinterpret_cast<float4*>(part + base + (size_t)b * FFN_)[threadIdx.x] = acc[b];
}

__global__ __launch_bounds__(256) void k_ffn_ns_r1(const float* __restrict__ part,
                                                   const float* __restrict__ b1,
                                                   float* __restrict__ tns) {
  int gid = blockIdx.x * 256 + threadIdx.x;  // 4*16*1024 float4 = 65536
  int o4 = gid & 1023;
  int b = (gid >> 10) & 3;
  int n = gid >> 12;
  float4 bb = *reinterpret_cast<const float4*>(b1 + (size_t)n * FFN_ + (size_t)o4 * 4);
  float4 s = bb;
  for (int c = 0; c < 8; ++c) {
    size_t pidx = (((size_t)n * 8 + c) * 4 + b) * FFN_ + (size_t)o4 * 4;
    float4 p = *reinterpret_cast<const float4*>(part + pidx);
    s.x += p.x; s.y += p.y; s.z += p.z; s.w += p.w;
  }
  s.x = fmaxf(s.x, 0.f); s.y = fmaxf(s.y, 0.f);
  s.z = fmaxf(s.z, 0.f); s.w = fmaxf(s.w, 0.f);
  *reinterpret_cast<float4*>(tns + ((size_t)(b * NS_ + n)) * FFN_ + (size_t)o4 * 4) = s;
}

// w2: grid (chunk=16, n=16), K-chunk = 256
__global__ __launch_bounds__(256) void k_ffn_ns_p2(const float* __restrict__ tns,
                                                   const float* __restrict__ w2,
                                                   float* __restrict__ part) {
  int chunk = blockIdx.x, n = blockIdx.y;
  __shared__ float xs[4][256];
  int i0 = chunk * 256;
  for (int idx = threadIdx.x; idx < 1024; idx += 256) {
    int b = idx >> 8, ii = idx & 255;
    xs[b][ii] = tns[((size_t)(b * NS_ + n)) * FFN_ + i0 + ii];
  }
  __syncthreads();
  float4 acc[4];
#pragma unroll
  for (int b = 0; b < 4; ++b) acc[b] = make_float4(0.f, 0.f, 0.f, 0.f);
  const float4* Wp = reinterpret_cast<const float4*>(w2 + (size_t)n * FFN_ * D_ + (size_t)i0 * D_) + threadIdx.x;
#pragma unroll 4
  for (int ii = 0; ii < 256; ++ii) {
    float4 w4 = Wp[(size_t)ii * (D_ / 4)];
#pragma unroll
    for (int b = 0; b < 4; ++b) {
      float xv = xs[b][ii];
      acc[b].x = fmaf(xv, w4.x, acc[b].x);
      acc[b].y = fmaf(xv, w4.y, acc[b].y);
      acc[b].z = fmaf(xv, w4.z, acc[b].z);
      acc[b].w = fmaf(xv, w4.w, acc[b].w);
    }
  }
  size_t base = (((size_t)n * 16 + chunk) * 4) * D_;
#pragma unroll
  for (int b = 0; b < 4; ++b)
    reinterpret_cast<float4*>(part + base + (size_t)b * D_)[threadIdx.x] = acc[b];
}

__global__ __launch_bounds__(256) void k_ffn_ns_r2(const float* __restrict__ part,
                                                   const float* __restrict__ b2,
                                                   const float* __restrict__ h1,
                                                   float* __restrict__ out) {
  int gid = blockIdx.x * 256 + threadIdx.x;  // 4*16*256 float4 = 16384
  int o4 = gid & 255;
  int b = (gid >> 8) & 3;
  int n = gid >> 10;
  size_t orow = ((size_t)(b * QL_ + OUT_ + n)) * D_ + (size_t)o4 * 4;
  float4 bb = *reinterpret_cast<const float4*>(b2 + (size_t)n * D_ + (size_t)o4 * 4);
  float4 hh = *reinterpret_cast<const float4*>(h1 + orow);
  float4 s;
  s.x = bb.x + hh.x; s.y = bb.y + hh.y; s.z = bb.z + hh.z; s.w = bb.w + hh.w;
  for (int c = 0; c < 16; ++c) {
    size_t pidx = (((size_t)n * 16 + c) * 4 + b) * D_ + (size_t)o4 * 4;
    float4 p = *reinterpret_cast<const float4*>(part + pidx);
    s.x += p.x; s.y += p.y; s.z += p.z; s.w += p.w;
  }
  *reinterpret_cast<float4*>(out + orow) = s;
}

// ---------------- tail: second output ----------------
__global__ void k_tail(const int* __restrict__ seq, float* __restrict__ out) {
  if (threadIdx.x < 4) {
    int v = seq[threadIdx.x];
    out[(size_t)B_ * QL_ * D_ + threadIdx.x] = (float)(v < OUT_ ? v : OUT_);
  }
}

extern "C" void kernel_launch(void* const* d_in, const int* in_sizes, int n_in,
                              void* d_out, int out_size, void* d_ws, size_t ws_size,
                              hipStream_t stream) {
  (void)in_sizes; (void)n_in; (void)out_size; (void)ws_size;
  const float* x    = (const float*)d_in[0];
  const int*   seq  = (const int*)d_in[1];
  const float* wqkv = (const float*)d_in[2];
  const float* bqkv = (const float*)d_in[3];
  const float* wnsq = (const float*)d_in[4];
  const float* bnsq = (const float*)d_in[5];
  const float* wnsk = (const float*)d_in[6];
  const float* bnsk = (const float*)d_in[7];
  const float* wnsv = (const float*)d_in[8];
  const float* bnsv = (const float*)d_in[9];
  const float* n1w  = (const float*)d_in[10];
  const float* n2w  = (const float*)d_in[11];
  const float* fw1  = (const float*)d_in[12];
  const float* fb1  = (const float*)d_in[13];
  const float* fw2  = (const float*)d_in[14];
  const float* fb2  = (const float*)d_in[15];
  const float* w1ns = (const float*)d_in[16];
  const float* b1ns = (const float*)d_in[17];
  const float* w2ns = (const float*)d_in[18];
  const float* b2ns = (const float*)d_in[19];
  float* out = (float*)d_out;
  float* ws  = (float*)d_ws;

  float* xn   = ws + OFF_XN;
  float* ts   = ws + OFF_TS;
  float* tns  = ws + OFF_TNS;
  float* pf1  = ws + OFF_PF1;
  float* pf2  = ws + OFF_PF2;
  float* qb   = ws + OFF_Q;
  float* kb   = ws + OFF_K;
  float* vb   = ws + OFF_V;
  float* h1   = ws + OFF_H1;
  float* hn   = ws + OFF_HN;
  float* pqkv = ws + OFF_PQKV;

  // 1. RMSNorm1 over all rows
  k_rmsnorm<<<B_ * TOTAL_, 256, 0, stream>>>(x, n1w, xn);

  // 2. QKV GEMM (M=8192, N=3072, K=1024) with scatter epilogue
  sgemm<128, 128, 8, 8, 0><<<dim3(3 * D_ / 128, B_ * MAX_ / 128), 256, 0, stream>>>(
      xn, wqkv, bqkv, qb, kb, vb, nullptr, B_ * MAX_, 3 * D_, D_);

  // 3. ns q/k/v projections (split-K streaming) + reduce
  k_nsproj_partial<<<dim3(8, NS_, 3), 256, 0, stream>>>(xn, wnsq, wnsk, wnsv, pqkv);
  k_nsproj_reduce<<<192, 256, 0, stream>>>(pqkv, bnsq, bnsk, bnsv, qb, kb, vb);

  // 4. RoPE
  k_rope<<<B_ * QL_, 256, 0, stream>>>(qb, QL_, MAX_ - OUT_);
  k_rope<<<B_ * TOTAL_, 256, 0, stream>>>(kb, TOTAL_, 0);

  // 5. attention -> h1 buffer (attn output)
  k_attn<<<dim3(QL_ / 16, H_, B_), 256, 0, stream>>>(qb, kb, vb, seq, h1);

  // 6. residual + RMSNorm2
  k_resid_rms<<<B_ * QL_, 256, 0, stream>>>(x, n2w, h1, hn);

  // 7. FFN shared path
  sgemm<128, 128, 8, 8, 1><<<dim3(FFN_ / 128, B_ * OUT_ / 128), 256, 0, stream>>>(
      hn, fw1, fb1, ts, nullptr, nullptr, nullptr, B_ * OUT_, FFN_, D_);
  sgemm<64, 64, 4, 4, 2><<<dim3(D_ / 64, B_ * OUT_ / 64), 256, 0, stream>>>(
      ts, fw2, fb2, out, nullptr, nullptr, h1, B_ * OUT_, D_, FFN_);

  // 8. FFN ns path (split-K streaming)
  k_ffn_ns_p1<<<dim3(8, 4, NS_), 256, 0, stream>>>(hn, w1ns, pf1);
  k_ffn_ns_r1<<<256, 256, 0, stream>>>(pf1, b1ns, tns);
  k_ffn_ns_p2<<<dim3(16, NS_), 256, 0, stream>>>(tns, w2ns, pf2);
  k_ffn_ns_r2<<<64, 256, 0, stream>>>(pf2, b2ns, h1, out);

  // 9. second output
  k_tail<<<1, 64, 0, stream>>>(seq, out);
}